// Round 8
// baseline (773.738 us; speedup 1.0000x reference)
//
#include <hip/hip_runtime.h>

#define N_NODES 100000
#define N_EDGES 1250000
#define FEATS 64

#define NPB   128                              // nodes per bucket
#define NBUCK ((N_NODES + NPB - 1) / NPB)      // 782
#define CAP   2304                             // slots/bucket; avg 1600, sigma 40 -> +17 sigma
#define TILE  4096
#define NTILES ((N_EDGES + TILE - 1) / TILE)   // 306

// ---------------------------------------------------------------------------
// ws layout:
//   cursor [1024]                 bucket write cursors (init: b*CAP)
//   pairs  int2[NBUCK*CAP + 64]   bucketed (dst,src) pairs (~14.4 MB)
// ---------------------------------------------------------------------------

__global__ __launch_bounds__(1024) void init_kernel(int* __restrict__ cursor) {
    int t = threadIdx.x;
    if (t < NBUCK) cursor[t] = t * CAP;
}

// Bin edges into 782 buckets by dst>>7. Per tile: LDS histogram -> local rank,
// one global atomicAdd per (tile,bucket) reserves a dense run.
__global__ __launch_bounds__(256) void binA_kernel(
        const int* __restrict__ src,
        const int* __restrict__ dst,
        int* __restrict__ cursor,
        int2* __restrict__ pairs) {
    __shared__ int hist[NBUCK];
    __shared__ int base[NBUCK];
    const int t  = threadIdx.x;
    const int e0 = blockIdx.x * TILE + t * 16;
    const bool full = (blockIdx.x + 1) * TILE <= N_EDGES;

    for (int i = t; i < NBUCK; i += 256) hist[i] = 0;
    __syncthreads();

    int d[16], lr[16];
    if (full) {
#pragma unroll
        for (int q = 0; q < 4; ++q) {
            int4 v = *(const int4*)(dst + e0 + q * 4);
            d[q * 4 + 0] = v.x; d[q * 4 + 1] = v.y;
            d[q * 4 + 2] = v.z; d[q * 4 + 3] = v.w;
        }
#pragma unroll
        for (int j = 0; j < 16; ++j) lr[j] = atomicAdd(&hist[d[j] >> 7], 1);
    } else {
#pragma unroll
        for (int j = 0; j < 16; ++j) {
            if (e0 + j < N_EDGES) {
                d[j]  = dst[e0 + j];
                lr[j] = atomicAdd(&hist[d[j] >> 7], 1);
            }
        }
    }
    __syncthreads();

    for (int i = t; i < NBUCK; i += 256)
        base[i] = hist[i] ? atomicAdd(&cursor[i], hist[i]) : 0;
    __syncthreads();

    if (full) {
        int s[16];
#pragma unroll
        for (int q = 0; q < 4; ++q) {
            int4 v = *(const int4*)(src + e0 + q * 4);
            s[q * 4 + 0] = v.x; s[q * 4 + 1] = v.y;
            s[q * 4 + 2] = v.z; s[q * 4 + 3] = v.w;
        }
#pragma unroll
        for (int j = 0; j < 16; ++j) {
            int bk  = d[j] >> 7;
            int pos = base[bk] + lr[j];
            if (pos < (bk + 1) * CAP)           // overflow guard (never hits)
                pairs[pos] = make_int2(d[j], s[j]);
        }
    } else {
#pragma unroll
        for (int j = 0; j < 16; ++j) {
            if (e0 + j < N_EDGES) {
                int bk  = d[j] >> 7;
                int pos = base[bk] + lr[j];
                if (pos < (bk + 1) * CAP)
                    pairs[pos] = make_int2(d[j], src[e0 + j]);
            }
        }
    }
}

// ---------------------------------------------------------------------------
// Fused: per-bucket LDS aggregation + linear + bias + relu.
// One block per bucket (128 nodes). Edge-parallel: each wave stages 64 pairs,
// unrolled x4 -> 4 independent h-row loads in flight; accumulate via
// ds_add_f32 (bank = lane%32, 2-way aliasing = free). Then 128x64 @ 64x64
// linear with W rows in VGPRs (launch_bounds(256,3) prevents wr[] spill).
// ---------------------------------------------------------------------------
__global__ __launch_bounds__(256, 3) void agg_linear_kernel(
        const float* __restrict__ h,
        const int2* __restrict__ pairs,
        const int* __restrict__ cursor,
        const float* __restrict__ W,    // [o][k] row-major
        const float* __restrict__ bias,
        float* __restrict__ out) {
    __shared__ float accum[NPB][FEATS];              // 32 KB
    __shared__ __align__(16) int2 stage[4][64];      // 2 KB

    const int tid  = threadIdx.x;
    const int lane = tid & 63;
    const int wv   = tid >> 6;
    const int b    = blockIdx.x;

    // zero accumulator
    {
        float4* ac = (float4*)&accum[0][0];
        float4 z = make_float4(0.f, 0.f, 0.f, 0.f);
        for (int i = tid; i < NPB * FEATS / 4; i += 256) ac[i] = z;
    }

    // W row for o = lane into registers; bias
    float wr[FEATS];
#pragma unroll
    for (int kk = 0; kk < 16; ++kk) {
        float4 w4 = *(const float4*)(W + (size_t)lane * FEATS + kk * 4);
        wr[kk * 4 + 0] = w4.x;
        wr[kk * 4 + 1] = w4.y;
        wr[kk * 4 + 2] = w4.z;
        wr[kk * 4 + 3] = w4.w;
    }
    const float bv = bias[lane];

    const int2* bp  = pairs + (size_t)b * CAP;
    const int size  = cursor[b] - b * CAP;
    __syncthreads();   // accum zeroed before any ds_add

    const int4* sp = (const int4*)&stage[wv][0];
    for (int base = wv * 64; base < size; base += 256) {
        int m = size - base;
        if (m > 64) m = 64;
        stage[wv][lane] = (lane < m) ? bp[base + lane] : make_int2(0, 0);
        // wave-private staging: in-wave DS ordering, no barrier needed
        for (int t = 0; t < m; t += 4) {
            int4 a = sp[t >> 1];
            int4 c = sp[(t >> 1) + 1];
            int d0 = a.x & (NPB - 1), s0 = a.y;
            int d1 = a.z & (NPB - 1), s1 = a.w;
            int d2 = c.x & (NPB - 1), s2 = c.y;
            int d3 = c.z & (NPB - 1), s3 = c.w;
            // 4 independent gathers in flight
            float v0 = h[(size_t)s0 * FEATS + lane];
            float v1 = h[(size_t)s1 * FEATS + lane];
            float v2 = h[(size_t)s2 * FEATS + lane];
            float v3 = h[(size_t)s3 * FEATS + lane];
            atomicAdd(&accum[d0][lane], v0);
            if (t + 1 < m) atomicAdd(&accum[d1][lane], v1);
            if (t + 2 < m) atomicAdd(&accum[d2][lane], v2);
            if (t + 3 < m) atomicAdd(&accum[d3][lane], v3);
        }
    }
    __syncthreads();   // all adds visible before linear

    // linear: 4 waves x 32 nodes; lane = output feature
    for (int ln = wv; ln < NPB; ln += 4) {
        int node = b * NPB + ln;
        if (node >= N_NODES) break;
        const float4* ar = (const float4*)&accum[ln][0];
        float o_acc = bv;
#pragma unroll
        for (int k4 = 0; k4 < 16; ++k4) {
            float4 r = ar[k4];                 // b128 broadcast
            o_acc = fmaf(r.x, wr[k4 * 4 + 0], o_acc);
            o_acc = fmaf(r.y, wr[k4 * 4 + 1], o_acc);
            o_acc = fmaf(r.z, wr[k4 * 4 + 2], o_acc);
            o_acc = fmaf(r.w, wr[k4 * 4 + 3], o_acc);
        }
        out[(size_t)node * FEATS + lane] = fmaxf(o_acc, 0.0f);
    }
}

extern "C" void kernel_launch(void* const* d_in, const int* in_sizes, int n_in,
                              void* d_out, int out_size, void* d_ws, size_t ws_size,
                              hipStream_t stream) {
    const float* h   = (const float*)d_in[0];
    const int*   src = (const int*)d_in[1];
    const int*   dst = (const int*)d_in[2];
    const float* W   = (const float*)d_in[3];
    const float* b   = (const float*)d_in[4];
    float* out = (float*)d_out;

    int*  cursor = (int*)d_ws;                 // 1024 ints
    int2* pairs  = (int2*)(cursor + 1024);     // NBUCK*CAP + pad

    init_kernel<<<1, 1024, 0, stream>>>(cursor);
    binA_kernel<<<NTILES, 256, 0, stream>>>(src, dst, cursor, pairs);
    agg_linear_kernel<<<NBUCK, 256, 0, stream>>>(h, pairs, cursor, W, b, out);
}

// Round 9
// 197.646 us; speedup vs baseline: 3.9148x; 3.9148x over previous
//
#include <hip/hip_runtime.h>

#define N_NODES 100000
#define N_EDGES 1250000
#define FEATS 64

#define NPB   256                              // nodes per bucket (= blockDim of binB)
#define NBUCK ((N_NODES + NPB - 1) / NPB)      // 391
#define CAP   4096                             // slots/bucket; avg 3197, +16 sigma
#define TILE  2048
#define NTILES ((N_EDGES + TILE - 1) / TILE)   // 611

// ---------------------------------------------------------------------------
// ws layout (ints):
//   cursor [512]          bucket sizes (memset 0; binA atomicAdd, relative)
//   offs   [100004]       CSR row offsets
//   csr_src[1250000]      src ids grouped by dst
//   pairs  int2[391*4096] bucketed (dst,src) pairs (12.8 MB)
// ---------------------------------------------------------------------------

// Pass A: bin edges into 391 coarse buckets by dst>>8. LDS histogram gives
// per-edge local rank; one global atomicAdd per (tile,bucket) reserves a run.
__global__ __launch_bounds__(256) void binA_kernel(
        const int* __restrict__ src,
        const int* __restrict__ dst,
        int* __restrict__ cursor,
        int2* __restrict__ pairs) {
    __shared__ int hist[NBUCK];
    __shared__ int base[NBUCK];
    const int t  = threadIdx.x;
    const int e0 = blockIdx.x * TILE + t * 8;
    const bool full = (blockIdx.x + 1) * TILE <= N_EDGES;

    for (int i = t; i < NBUCK; i += 256) hist[i] = 0;
    __syncthreads();

    int d[8], lr[8];
    if (full) {
        int4 a = *(const int4*)(dst + e0);
        int4 q = *(const int4*)(dst + e0 + 4);
        d[0]=a.x; d[1]=a.y; d[2]=a.z; d[3]=a.w;
        d[4]=q.x; d[5]=q.y; d[6]=q.z; d[7]=q.w;
#pragma unroll
        for (int j = 0; j < 8; ++j) lr[j] = atomicAdd(&hist[d[j] >> 8], 1);
    } else {
#pragma unroll
        for (int j = 0; j < 8; ++j) {
            if (e0 + j < N_EDGES) {
                d[j]  = dst[e0 + j];
                lr[j] = atomicAdd(&hist[d[j] >> 8], 1);
            }
        }
    }
    __syncthreads();

    for (int i = t; i < NBUCK; i += 256)
        base[i] = hist[i] ? atomicAdd(&cursor[i], hist[i]) : 0;   // relative
    __syncthreads();

    if (full) {
        int4 a = *(const int4*)(src + e0);
        int4 q = *(const int4*)(src + e0 + 4);
        int s[8] = {a.x, a.y, a.z, a.w, q.x, q.y, q.z, q.w};
#pragma unroll
        for (int j = 0; j < 8; ++j) {
            int bk  = d[j] >> 8;
            int rel = base[bk] + lr[j];
            if (rel < CAP)                       // overflow guard (never hits)
                pairs[(size_t)bk * CAP + rel] = make_int2(d[j], s[j]);
        }
    } else {
#pragma unroll
        for (int j = 0; j < 8; ++j) {
            if (e0 + j < N_EDGES) {
                int bk  = d[j] >> 8;
                int rel = base[bk] + lr[j];
                if (rel < CAP)
                    pairs[(size_t)bk * CAP + rel] = make_int2(d[j], src[e0 + j]);
            }
        }
    }
}

// Pass B: one block per bucket. eb = sum of sizes of earlier buckets (in-block
// reduction, replaces the bscan launch). LDS count + scan over 256 local
// nodes -> coalesced offs slice; scatter src into the bucket's contiguous,
// single-block-owned csr region.
__global__ __launch_bounds__(256) void binB_kernel(
        const int2* __restrict__ pairs,
        const int* __restrict__ cursor,
        int* __restrict__ offs,
        int* __restrict__ csr_src) {
    __shared__ int red[256];
    __shared__ int lcnt[NPB];
    __shared__ int lsum[NPB];
    __shared__ int lcur[NPB];
    const int t = threadIdx.x;
    const int b = blockIdx.x;

    // eb = sum_{i<b} cursor[i]   (b <= 390 -> at most 2 loads/thread)
    int part = 0;
    for (int i = t; i < b; i += 256) part += cursor[i];
    red[t] = part;
    __syncthreads();
    for (int o = 128; o > 0; o >>= 1) {
        if (t < o) red[t] += red[t + o];
        __syncthreads();
    }
    const int eb   = red[0];
    const int size = cursor[b];
    const int2* bp = pairs + (size_t)b * CAP;

    lcnt[t] = 0;
    __syncthreads();
    for (int i = t; i < size; i += 256) atomicAdd(&lcnt[bp[i].x & (NPB - 1)], 1);
    __syncthreads();

    lsum[t] = lcnt[t];
    __syncthreads();
    for (int off = 1; off < NPB; off <<= 1) {
        int y = (t >= off) ? lsum[t - off] : 0;
        __syncthreads();
        lsum[t] += y;
        __syncthreads();
    }
    const int excl = (t > 0) ? lsum[t - 1] : 0;
    lcur[t] = excl;
    const int node = b * NPB + t;
    if (node < N_NODES) offs[node] = eb + excl;
    if (b == 0 && t == 0) offs[N_NODES] = N_EDGES;
    __syncthreads();

    for (int i = t; i < size; i += 256) {
        int2 p = bp[i];
        int r = atomicAdd(&lcur[p.x & (NPB - 1)], 1);
        csr_src[eb + r] = p.y;
    }
}

// ---------------------------------------------------------------------------
// Fused gather + linear + bias + relu.
// One node per 16-lane GROUP (4 nodes/wave): no wave-serial per-node chain.
// Each lane owns 4 feats (float4) of its group's node; edge loop unrolled x2
// -> 8 independent h-row loads in flight. No cross-lane reduction needed.
// ---------------------------------------------------------------------------
__global__ __launch_bounds__(256) void gather_linear_kernel(
        const float* __restrict__ h,
        const int* __restrict__ offs,
        const int* __restrict__ csr_src,
        const float* __restrict__ W,    // [o][k] row-major
        const float* __restrict__ b,
        float* __restrict__ out) {
    __shared__ int   sidx[4][4][16];     // [wave][group][slot]
    __shared__ float srow[4][4][FEATS];  // [wave][group][feat]

    const int tid  = threadIdx.x;
    const int lane = tid & 63;
    const int wv   = tid >> 6;
    const int g    = lane >> 4;          // group 0..3
    const int li   = lane & 15;
    const int fo   = li * 4;

    float wr[FEATS];
#pragma unroll
    for (int kk = 0; kk < 16; ++kk) {
        float4 w4 = *(const float4*)(W + (size_t)lane * FEATS + kk * 4);
        wr[kk * 4 + 0] = w4.x;
        wr[kk * 4 + 1] = w4.y;
        wr[kk * 4 + 2] = w4.z;
        wr[kk * 4 + 3] = w4.w;
    }
    const float bias = b[lane];

    const int stride = gridDim.x * 16;   // 4 waves * 4 groups per block
    for (int n0 = blockIdx.x * 16 + wv * 4; n0 < N_NODES; n0 += stride) {
        const int n = n0 + g;
        const bool valid = (n < N_NODES);
        const int beg = valid ? offs[n] : 0;
        const int end = valid ? offs[n + 1] : 0;
        const int m   = end - beg;

        float4 acc0 = make_float4(0.f, 0.f, 0.f, 0.f);
        float4 acc1 = make_float4(0.f, 0.f, 0.f, 0.f);
        for (int base = 0; __any(base < m); base += 16) {
            sidx[wv][g][li] = (base + li < m) ? csr_src[beg + base + li] : 0;
            // in-wave DS write->read ordering; no barrier needed
#pragma unroll
            for (int t = 0; t < 16; t += 2) {
                int r0 = sidx[wv][g][t];
                int r1 = sidx[wv][g][t + 1];
                if (base + t < m) {
                    float4 v = *(const float4*)(h + (size_t)r0 * FEATS + fo);
                    acc0.x += v.x; acc0.y += v.y; acc0.z += v.z; acc0.w += v.w;
                }
                if (base + t + 1 < m) {
                    float4 v = *(const float4*)(h + (size_t)r1 * FEATS + fo);
                    acc1.x += v.x; acc1.y += v.y; acc1.z += v.z; acc1.w += v.w;
                }
            }
        }
        acc0.x += acc1.x; acc0.y += acc1.y; acc0.z += acc1.z; acc0.w += acc1.w;
        *(float4*)&srow[wv][g][fo] = acc0;

        // linear for this wave's 4 nodes; lane = output feature
#pragma unroll
        for (int gg = 0; gg < 4; ++gg) {
            int nn = n0 + gg;
            if (nn >= N_NODES) break;
            const float4* ar = (const float4*)&srow[wv][gg][0];
            float o_acc = bias;
#pragma unroll
            for (int k4 = 0; k4 < 16; ++k4) {
                float4 r = ar[k4];               // b128 broadcast
                o_acc = fmaf(r.x, wr[k4 * 4 + 0], o_acc);
                o_acc = fmaf(r.y, wr[k4 * 4 + 1], o_acc);
                o_acc = fmaf(r.z, wr[k4 * 4 + 2], o_acc);
                o_acc = fmaf(r.w, wr[k4 * 4 + 3], o_acc);
            }
            out[(size_t)nn * FEATS + lane] = fmaxf(o_acc, 0.0f);
        }
    }
}

extern "C" void kernel_launch(void* const* d_in, const int* in_sizes, int n_in,
                              void* d_out, int out_size, void* d_ws, size_t ws_size,
                              hipStream_t stream) {
    const float* h   = (const float*)d_in[0];
    const int*   src = (const int*)d_in[1];
    const int*   dst = (const int*)d_in[2];
    const float* W   = (const float*)d_in[3];
    const float* b   = (const float*)d_in[4];
    float* out = (float*)d_out;

    int*  cursor  = (int*)d_ws;                 // 512
    int*  offs    = cursor + 512;               // 100004
    int*  csr_src = offs + 100004;              // 1250000
    int2* pairs   = (int2*)(csr_src + N_EDGES); // 391*4096 int2 (8B-aligned)

    hipMemsetAsync(cursor, 0, 512 * sizeof(int), stream);
    binA_kernel<<<NTILES, 256, 0, stream>>>(src, dst, cursor, pairs);
    binB_kernel<<<NBUCK, 256, 0, stream>>>(pairs, cursor, offs, csr_src);
    gather_linear_kernel<<<1563, 256, 0, stream>>>(h, offs, csr_src, W, b, out);
}